// Round 1
// baseline (793.558 us; speedup 1.0000x reference)
//
#include <hip/hip_runtime.h>
#include <stdint.h>

// Problem dims: B=8, T=16, D=2048, H=16, HD=128, CACHE=4096
// pairs = B*H = 128, rows = B*T = 128, keys total = 4112
#define NSPLIT 33
#define SCALE 0.08838834764831845f   // 1/sqrt(128)
#define LOG2E 1.4426950408889634f

using f32x4  = __attribute__((ext_vector_type(4))) float;
using bf16x8 = __attribute__((ext_vector_type(8))) short;
using bf16x4 = __attribute__((ext_vector_type(4))) short;

__device__ __forceinline__ unsigned short f2bf(float f) {
    uint32_t u = __builtin_bit_cast(uint32_t, f);
    u = (u + 0x7FFFu + ((u >> 16) & 1u)) >> 16;   // round-to-nearest-even
    return (unsigned short)u;
}

// ---------------- x -> bf16 ----------------
__global__ __launch_bounds__(256) void cvt_x_kernel(const float* __restrict__ x,
                                                    unsigned short* __restrict__ xb) {
    int i = (blockIdx.x * 256 + threadIdx.x) * 8;
    f32x4 a = *(const f32x4*)(x + i);
    f32x4 b = *(const f32x4*)(x + i + 4);
    bf16x8 o;
    o[0]=f2bf(a[0]); o[1]=f2bf(a[1]); o[2]=f2bf(a[2]); o[3]=f2bf(a[3]);
    o[4]=f2bf(b[0]); o[5]=f2bf(b[1]); o[6]=f2bf(b[2]); o[7]=f2bf(b[3]);
    *(bf16x8*)(xb + i) = o;
}

// ---------------- GEMM: out = xb[128,2048] @ W^T + bias ----------------
// MODE 0: QKV fused. grid=96: mat=jb>>5 (Wq/Wk/Wv), jj=jb&31. Output [B,H,T,HD].
// MODE 1: Wo proj. grid=32. Output row-major [128][2048] to d_out.
// Block tile 128x64, 4 waves as 2Mx2N (wave tile 64x32, acc[4][2]), K-chunks of 64.
template<int MODE>
__global__ __launch_bounds__(256) void gemm_kernel(
    const unsigned short* __restrict__ xb,
    const float* __restrict__ W0, const float* __restrict__ W1, const float* __restrict__ W2,
    const float* __restrict__ b0, const float* __restrict__ b1, const float* __restrict__ b2,
    float* __restrict__ o0, float* __restrict__ o1, float* __restrict__ o2)
{
    __shared__ unsigned short xt[128][72];  // +8 pad: bank-conflict-free b128 frag reads
    __shared__ unsigned short wt[64][72];
    const int t = threadIdx.x;
    const int jb = blockIdx.x;
    int jj = jb;
    const float* W = W0; const float* bias = b0; float* outp = o0;
    if (MODE == 0) {
        int mat = jb >> 5; jj = jb & 31;
        W    = (mat == 0) ? W0 : ((mat == 1) ? W1 : W2);
        bias = (mat == 0) ? b0 : ((mat == 1) ? b1 : b2);
        outp = (mat == 0) ? o0 : ((mat == 1) ? o1 : o2);
    }
    const int lane = t & 63, w = t >> 6;
    const int wm = w >> 1, wn = w & 1;
    const int g = lane >> 4, lr = lane & 15;

    f32x4 acc[4][2] = {};
    for (int kc = 0; kc < 2048; kc += 64) {
        // stage x tile [128][64] bf16 (coalesced 16B per lane)
        #pragma unroll
        for (int j = 0; j < 4; j++) {
            int row = j * 32 + (t >> 3);
            int col = (t & 7) * 8;
            *(bf16x8*)&xt[row][col] = *(const bf16x8*)(xb + row * 2048 + kc + col);
        }
        // stage W tile [64][64]: f32 global -> bf16 LDS
        #pragma unroll
        for (int j = 0; j < 4; j++) {
            int row = j * 16 + (t >> 4);
            int col = (t & 15) * 4;
            f32x4 v = *(const f32x4*)(W + (size_t)(jj * 64 + row) * 2048 + kc + col);
            bf16x4 o; o[0]=f2bf(v[0]); o[1]=f2bf(v[1]); o[2]=f2bf(v[2]); o[3]=f2bf(v[3]);
            *(bf16x4*)&wt[row][col] = o;
        }
        __syncthreads();
        #pragma unroll
        for (int ks = 0; ks < 64; ks += 32) {
            bf16x8 af[4], bfr[2];
            #pragma unroll
            for (int m = 0; m < 4; m++) af[m] = *(const bf16x8*)&xt[wm*64 + m*16 + lr][ks + g*8];
            #pragma unroll
            for (int n = 0; n < 2; n++) bfr[n] = *(const bf16x8*)&wt[wn*32 + n*16 + lr][ks + g*8];
            #pragma unroll
            for (int m = 0; m < 4; m++)
                #pragma unroll
                for (int n = 0; n < 2; n++)
                    acc[m][n] = __builtin_amdgcn_mfma_f32_16x16x32_bf16(af[m], bfr[n], acc[m][n], 0, 0, 0);
        }
        __syncthreads();
    }
    // epilogue: C/D layout col=lane&15, row=(lane>>4)*4+reg (m89-verified)
    #pragma unroll
    for (int m = 0; m < 4; m++) {
        #pragma unroll
        for (int n = 0; n < 2; n++) {
            #pragma unroll
            for (int r = 0; r < 4; r++) {
                int row = wm*64 + m*16 + g*4 + r;      // 0..127 = b*16+t
                int cj  = jj*64 + wn*32 + n*16 + lr;   // 0..2047 within matrix
                float val = acc[m][n][r] + bias[cj];
                if (MODE == 1) {
                    outp[(size_t)row * 2048 + cj] = val;
                } else {
                    int bb = row >> 4, tt = row & 15;
                    int h = cj >> 7, hd = cj & 127;
                    outp[(size_t)((bb * 16 + h) * 16 + tt) * 128 + hd] = val;  // [B,H,T,HD]
                }
            }
        }
    }
}

// ---------------- flash-decode attention, split over keys ----------------
// grid (33, 128): blockIdx.x = split (32x128 cached keys + 1x16 new), blockIdx.y = pair (b*16+h)
__global__ __launch_bounds__(256) void attn_kernel(
    const float* __restrict__ qf,     // ws q  [pair][16][128] f32
    const float* __restrict__ Kc,     // [B,H,4096,128]
    const float* __restrict__ Vc,
    const float* __restrict__ knew,   // d_out k section [pair][16][128]
    const float* __restrict__ vnew,
    float* __restrict__ op,           // ws [pair][33][16][128] f32 partials
    float* __restrict__ ml)           // ws [pair][33][{m[16],l[16]}]
{
    __shared__ unsigned short q_lds[16][136];
    __shared__ unsigned short kv_lds[128][136];  // K, then reused for V
    __shared__ float          s_lds[16][136];
    __shared__ unsigned short p_lds[16][136];

    const int t = threadIdx.x;
    const int sp = blockIdx.x;
    const int p  = blockIdx.y;
    const int lane = t & 63, w = t >> 6, g = lane >> 4, lr = lane & 15;
    const int nk = (sp < 32) ? 128 : 16;
    const float* Ksrc = (sp < 32) ? (Kc + ((size_t)p * 4096 + sp * 128) * 128) : (knew + (size_t)p * 2048);
    const float* Vsrc = (sp < 32) ? (Vc + ((size_t)p * 4096 + sp * 128) * 128) : (vnew + (size_t)p * 2048);

    // stage q [16][128] f32 -> bf16 LDS
    {
        int row = t >> 4, col = (t & 15) * 8;
        const float* src = qf + (size_t)p * 2048 + row * 128 + col;
        f32x4 a = *(const f32x4*)(src);
        f32x4 b = *(const f32x4*)(src + 4);
        bf16x8 o;
        o[0]=f2bf(a[0]); o[1]=f2bf(a[1]); o[2]=f2bf(a[2]); o[3]=f2bf(a[3]);
        o[4]=f2bf(b[0]); o[5]=f2bf(b[1]); o[6]=f2bf(b[2]); o[7]=f2bf(b[3]);
        *(bf16x8*)&q_lds[row][col] = o;
    }
    // stage K tile (coalesced float4 per lane), zero-fill beyond nk
    #pragma unroll
    for (int j = 0; j < 16; j++) {
        int flat = j * 1024 + t * 4;
        int row = flat >> 7, col = flat & 127;
        bf16x4 o = {};
        if (row < nk) {
            f32x4 v = *(const f32x4*)(Ksrc + flat);
            o[0]=f2bf(v[0]); o[1]=f2bf(v[1]); o[2]=f2bf(v[2]); o[3]=f2bf(v[3]);
        }
        *(bf16x4*)&kv_lds[row][col] = o;
    }
    __syncthreads();

    // QK^T: S^T[key][q] = K_tile . q^T ; wave w owns keys [w*32, w*32+32)
    f32x4 sacc[2] = {};
    #pragma unroll
    for (int ks = 0; ks < 4; ks++) {
        bf16x8 bq = *(const bf16x8*)&q_lds[lr][ks*32 + g*8];
        #pragma unroll
        for (int m = 0; m < 2; m++) {
            bf16x8 ak = *(const bf16x8*)&kv_lds[w*32 + m*16 + lr][ks*32 + g*8];
            sacc[m] = __builtin_amdgcn_mfma_f32_16x16x32_bf16(ak, bq, sacc[m], 0, 0, 0);
        }
    }
    #pragma unroll
    for (int m = 0; m < 2; m++)
        #pragma unroll
        for (int r = 0; r < 4; r++)
            s_lds[lr][w*32 + m*16 + g*4 + r] = sacc[m][r];
    __syncthreads();   // all QK reads of kv_lds done; s_lds visible

    // issue V global loads early (latency hidden under softmax)
    f32x4 vreg[16];
    #pragma unroll
    for (int j = 0; j < 16; j++) {
        int flat = j * 1024 + t * 4;
        int row = flat >> 7;
        f32x4 v = {};
        if (row < nk) v = *(const f32x4*)(Vsrc + flat);
        vreg[j] = v;
    }

    // softmax over this split's keys: thread t -> q=t>>4, keys (t&15)*8..+7
    {
        const int q = t >> 4, i = t & 15;
        float sv[8];
        #pragma unroll
        for (int e = 0; e < 8; e++) sv[e] = s_lds[q][i*8 + e];
        float mx = -1e30f;
        const bool live = (i * 8) < nk;
        if (live) {
            #pragma unroll
            for (int e = 0; e < 8; e++) mx = fmaxf(mx, sv[e]);
        }
        #pragma unroll
        for (int d = 1; d < 16; d <<= 1) mx = fmaxf(mx, __shfl_xor(mx, d, 16));
        const float c = SCALE * LOG2E;
        float lsum = 0.f;
        bf16x8 o;
        if (live) {
            #pragma unroll
            for (int e = 0; e < 8; e++) {
                float pe = exp2f((sv[e] - mx) * c);
                lsum += pe;
                o[e] = (short)f2bf(pe);
            }
        } else {
            #pragma unroll
            for (int e = 0; e < 8; e++) o[e] = 0;
        }
        #pragma unroll
        for (int d = 1; d < 16; d <<= 1) lsum += __shfl_xor(lsum, d, 16);
        *(bf16x8*)&p_lds[q][i*8] = o;
        if (i == 0) {
            ml[((size_t)p * NSPLIT + sp) * 32 + q]      = mx * SCALE;  // scaled running max
            ml[((size_t)p * NSPLIT + sp) * 32 + 16 + q] = lsum;
        }
    }
    // write V into kv_lds (safe: QK reads finished before previous barrier)
    #pragma unroll
    for (int j = 0; j < 16; j++) {
        int flat = j * 1024 + t * 4;
        int row = flat >> 7, col = flat & 127;
        bf16x4 o;
        o[0]=f2bf(vreg[j][0]); o[1]=f2bf(vreg[j][1]); o[2]=f2bf(vreg[j][2]); o[3]=f2bf(vreg[j][3]);
        *(bf16x4*)&kv_lds[row][col] = o;
    }
    __syncthreads();

    // PV: O[q][hd] += P[q][key] * V[key][hd]; wave w owns hd [w*32, w*32+32)
    f32x4 oacc[2] = {};
    #pragma unroll
    for (int ks = 0; ks < 4; ks++) {
        bf16x8 ap = *(const bf16x8*)&p_lds[lr][ks*32 + g*8];
        #pragma unroll
        for (int n = 0; n < 2; n++) {
            const int colhd = w*32 + n*16 + lr;
            bf16x8 bv;
            #pragma unroll
            for (int e = 0; e < 8; e++)
                bv[e] = (short)kv_lds[ks*32 + g*8 + e][colhd];
            oacc[n] = __builtin_amdgcn_mfma_f32_16x16x32_bf16(ap, bv, oacc[n], 0, 0, 0);
        }
    }
    const size_t base = ((size_t)p * NSPLIT + sp) * 16 * 128;
    #pragma unroll
    for (int n = 0; n < 2; n++)
        #pragma unroll
        for (int r = 0; r < 4; r++)
            op[base + (size_t)(g*4 + r) * 128 + w*32 + n*16 + lr] = oacc[n][r];
}

// ---------------- combine splits ----------------
__global__ __launch_bounds__(256) void combine_kernel(
    const float* __restrict__ op, const float* __restrict__ ml,
    unsigned short* __restrict__ attn)   // bf16 [128][2048] row-major (b*16+t, h*128+hd)
{
    const int p = blockIdx.x, t = threadIdx.x;
    const int q = t >> 4, i = t & 15;
    const float* mlb = ml + (size_t)p * NSPLIT * 32;
    float M = -1e30f;
    for (int s = 0; s < NSPLIT; s++) M = fmaxf(M, mlb[s*32 + q]);
    float L = 0.f;
    f32x4 a0 = {}, a1 = {};
    for (int s = 0; s < NSPLIT; s++) {
        float ms = mlb[s*32 + q];
        float ls = mlb[s*32 + 16 + q];
        float wgt = exp2f((ms - M) * LOG2E);
        L += wgt * ls;
        const float* ob = op + (((size_t)p * NSPLIT + s) * 16 + q) * 128 + i * 8;
        f32x4 v0 = *(const f32x4*)(ob);
        f32x4 v1 = *(const f32x4*)(ob + 4);
        a0 += wgt * v0;
        a1 += wgt * v1;
    }
    const float inv = 1.f / L;
    const int b = p >> 4, h = p & 15;
    bf16x8 o;
    o[0]=f2bf(a0[0]*inv); o[1]=f2bf(a0[1]*inv); o[2]=f2bf(a0[2]*inv); o[3]=f2bf(a0[3]*inv);
    o[4]=f2bf(a1[0]*inv); o[5]=f2bf(a1[1]*inv); o[6]=f2bf(a1[2]*inv); o[7]=f2bf(a1[3]*inv);
    *(bf16x8*)(attn + (size_t)(b*16 + q) * 2048 + h*128 + i*8) = o;
}

extern "C" void kernel_launch(void* const* d_in, const int* in_sizes, int n_in,
                              void* d_out, int out_size, void* d_ws, size_t ws_size,
                              hipStream_t stream) {
    const float* x  = (const float*)d_in[0];
    const float* Kc = (const float*)d_in[1];
    const float* Vc = (const float*)d_in[2];
    const float* Wq = (const float*)d_in[3];
    const float* bq = (const float*)d_in[4];
    const float* Wk = (const float*)d_in[5];
    const float* bk = (const float*)d_in[6];
    const float* Wv = (const float*)d_in[7];
    const float* bv = (const float*)d_in[8];
    const float* Wo = (const float*)d_in[9];
    const float* bo = (const float*)d_in[10];

    float* out   = (float*)d_out;          // [8,16,2048]
    float* k_out = out + 262144;           // [8,16,16,128] = [B,H,T,HD]
    float* v_out = out + 524288;

    char* ws = (char*)d_ws;
    unsigned short* ws_x    = (unsigned short*)(ws);             // 512 KB  x bf16
    unsigned short* ws_attn = (unsigned short*)(ws + 524288);    // 512 KB  attn out bf16
    float*          ws_q    = (float*)(ws + 1048576);            // 1 MB    q f32 [B,H,T,HD]
    float*          ws_ml   = (float*)(ws + 2097152);            // 528 KB  m,l per (pair,split)
    float*          ws_op   = (float*)(ws + 2637824);            // 34.6 MB o partials

    cvt_x_kernel<<<128, 256, 0, stream>>>(x, ws_x);
    gemm_kernel<0><<<96, 256, 0, stream>>>(ws_x, Wq, Wk, Wv, bq, bk, bv, ws_q, k_out, v_out);
    attn_kernel<<<dim3(NSPLIT, 128), 256, 0, stream>>>(ws_q, Kc, Vc, k_out, v_out, ws_op, ws_ml);
    combine_kernel<<<128, 256, 0, stream>>>(ws_op, ws_ml, ws_attn);
    gemm_kernel<1><<<32, 256, 0, stream>>>(ws_attn, Wo, nullptr, nullptr, bo, nullptr, nullptr,
                                           out, nullptr, nullptr);
}